// Round 2
// baseline (670.813 us; speedup 1.0000x reference)
//
#include <hip/hip_runtime.h>
#include <hip/hip_bf16.h>

// StackedLoRALinear on MI355X (gfx950). fp32 in/out, bf16 MFMA inside.
//
// Algebraic fold: out = x @ Weff^T + b, where
//   Weff = W + B' @ A_all,  B'[n,j=d*32+r] = lora_B[d,n,r],  A_all = lora_A flat [128,3072]
// Pipeline:
//   1. cvt x -> bf16 (8 elem/thread)
//   2. fused transpose-convert lora_B -> B' and lora_A -> A^T (bf16 [3072,128])
//   3. Weff = B' @ (A^T)^T + W  via 128^2 MFMA GEMM (KT=4, ADD_MAT, bf16 out)
//   4. out = xb @ Weff^T + b    via 256^2 deep-pipelined MFMA GEMM (fp32 out)
//
// Step 4 schedule (v2): stages clustered where buffers are released —
//   A-tile(cur) fully read by end of P2  -> stage A(t+2) at P3 (into cur)
//   B-tile(cur) fully read by end of P3  -> stage B(t+2) at P4 (into cur)
// Single s_waitcnt vmcnt(8) at end of P4 drains tile t+1 (issued a full
// K-tile earlier -> ~5 phases of slack vs HBM latency). Never vmcnt(0) in
// the main loop.

typedef unsigned short ushort_t;
typedef short bf16x8 __attribute__((ext_vector_type(8)));   // 8 bf16 = 4 VGPRs
typedef float floatx4 __attribute__((ext_vector_type(4)));
typedef unsigned short ushortx4 __attribute__((ext_vector_type(4)));
typedef unsigned short ushortx8 __attribute__((ext_vector_type(8)));

__device__ __forceinline__ ushort_t f2bf(float f) {
    __hip_bfloat16 h = __float2bfloat16(f);
    return *(ushort_t*)&h;
}

__device__ __forceinline__ void async_load16(const void* g, void* l) {
    __builtin_amdgcn_global_load_lds(
        (const __attribute__((address_space(1))) void*)g,
        (__attribute__((address_space(3))) void*)l,
        16, 0, 0);
}

#define MFMA16(a, b, c) __builtin_amdgcn_mfma_f32_16x16x32_bf16(a, b, c, 0, 0, 0)

// fp32 -> bf16, 8 elements/thread. n8 = n/8.
__global__ __launch_bounds__(256)
void cvt_kernel(const float* __restrict__ in, ushort_t* __restrict__ out, int n8) {
    int i = blockIdx.x * 256 + threadIdx.x;
    if (i < n8) {
        const float4 v0 = ((const float4*)in)[2 * i];
        const float4 v1 = ((const float4*)in)[2 * i + 1];
        ushortx8 o = { f2bf(v0.x), f2bf(v0.y), f2bf(v0.z), f2bf(v0.w),
                       f2bf(v1.x), f2bf(v1.y), f2bf(v1.z), f2bf(v1.w) };
        ((ushortx8*)out)[i] = o;
    }
}

// Fused LoRA factor transposes. Blocks [0,1536): B', blocks [1536,3072): A^T.
// B'[n*128 + d*32 + r] = bf16(lora_B[d*N*32 + n*32 + r]);  N=3072
// A^T[kk*128 + j]      = bf16(lora_A[j*3072 + kk]);  (lora_A flat = [128,3072])
__global__ __launch_bounds__(256)
void transpose_lora_kernel(const float* __restrict__ lb,
                           const float* __restrict__ la,
                           ushort_t* __restrict__ outB,
                           ushort_t* __restrict__ outA) {
    int bid = blockIdx.x;
    if (bid < 1536) {
        int idx = bid * 256 + threadIdx.x;      // 0 .. 393215
        int n = idx >> 7;
        int j = idx & 127;
        int d = j >> 5, r = j & 31;
        outB[idx] = f2bf(lb[(size_t)d * (3072 * 32) + (size_t)n * 32 + r]);
    } else {
        int idx = (bid - 1536) * 256 + threadIdx.x;
        int kk = idx >> 7;
        int j  = idx & 127;
        outA[idx] = f2bf(la[(size_t)j * 3072 + kk]);
    }
}

// ---------------------------------------------------------------------------
// 128^2 "B-transposed" GEMM (kept for the tiny Weff build, KT=4).
// ---------------------------------------------------------------------------
template <int KT, bool OUT_F32, bool ADD_MAT>
__global__ __launch_bounds__(256)
void gemm_bt_kernel(const ushort_t* __restrict__ A, int lda,
                    const ushort_t* __restrict__ B, int ldb,
                    const float* __restrict__ Cadd,   // [M,ldc] fp32 if ADD_MAT
                    const float* __restrict__ bias,   // [N] fp32 or null
                    void* __restrict__ Cv, int ldc)
{
    __shared__ ushort_t As[128 * 32];   // 8 KB
    __shared__ ushort_t Bs[128 * 32];   // 8 KB

    const int t    = threadIdx.x;
    const int lane = t & 63;
    const int wave = t >> 6;
    const int wr   = wave >> 1, wc = wave & 1;
    const int quad = lane >> 4, l16 = lane & 15;

    const int mBase = blockIdx.y * 128;
    const int nBase = blockIdx.x * 128;

    floatx4 acc[4][4] = {};

    const int p0 = t,       r0 = p0 >> 2, g0 = ((p0 & 3) ^ ((r0 >> 1) & 3)) << 3;
    const int p1 = t + 256, r1 = p1 >> 2, g1 = ((p1 & 3) ^ ((r1 >> 1) & 3)) << 3;
    const int qs = (quad ^ ((l16 >> 1) & 3)) << 3;

    for (int kt = 0; kt < KT; ++kt) {
        const int ko = kt * 32;

        async_load16(A + (size_t)(mBase + r0) * lda + ko + g0, &As[p0 * 8]);
        async_load16(A + (size_t)(mBase + r1) * lda + ko + g1, &As[p1 * 8]);
        async_load16(B + (size_t)(nBase + r0) * ldb + ko + g0, &Bs[p0 * 8]);
        async_load16(B + (size_t)(nBase + r1) * ldb + ko + g1, &Bs[p1 * 8]);

        __syncthreads();

        bf16x8 af[4], bf[4];
#pragma unroll
        for (int mi = 0; mi < 4; ++mi)
            af[mi] = *(const bf16x8*)&As[(wr * 64 + mi * 16 + l16) * 32 + qs];
#pragma unroll
        for (int ni = 0; ni < 4; ++ni)
            bf[ni] = *(const bf16x8*)&Bs[(wc * 64 + ni * 16 + l16) * 32 + qs];

#pragma unroll
        for (int mi = 0; mi < 4; ++mi)
#pragma unroll
            for (int ni = 0; ni < 4; ++ni)
                acc[mi][ni] = MFMA16(af[mi], bf[ni], acc[mi][ni]);

        __syncthreads();
    }

#pragma unroll
    for (int ni = 0; ni < 4; ++ni) {
        const int col = nBase + wc * 64 + ni * 16 + l16;
        const float bv = bias ? bias[col] : 0.0f;
#pragma unroll
        for (int mi = 0; mi < 4; ++mi) {
            const int row = mBase + wr * 64 + mi * 16 + quad * 4;
#pragma unroll
            for (int r = 0; r < 4; ++r) {
                float v = acc[mi][ni][r] + bv;
                if (ADD_MAT) v += Cadd[(size_t)(row + r) * ldc + col];
                if (OUT_F32) {
                    ((float*)Cv)[(size_t)(row + r) * ldc + col] = v;
                } else {
                    ((ushort_t*)Cv)[(size_t)(row + r) * ldc + col] = f2bf(v);
                }
            }
        }
    }
}

// ---------------------------------------------------------------------------
// Main GEMM: 256x256 tile, BK=64, 8 waves (2M x 4N), 4 phases/K-tile.
// C[m,n] = sum_k A[m,k]*B[n,k] + bias[n]; A=[16384,3072], B=[3072,3072] bf16.
//
// LDS (128 KiB): buf c at c*65536; A-tile at +0 (2 halves x 16 KiB = rows
// 0-127 / 128-255), B-tile at +32768. Slot p (16 B) at row=p>>3, chunk s=p&7
// holds global chunk s ^ (row&7) (XOR swizzle -> conflict-free ds_read_b128;
// write side linear for global_load_lds, source address pre-swizzled).
//
// Release/stage discipline (per iter t, buffer cur=t&1):
//   P1: read af[0..3]+bf[0..1]                          (A,B cur)
//   P2: read af[4..7]        -> A(cur) fully released
//   P3: read bf[2..3]; STAGE A(t+2) both halves -> cur  (B released after)
//   P4: STAGE B(t+2) both halves -> cur; MFMA from regs; vmcnt(8); barrier
// vmcnt(8): 16 loads in flight, drains the 8 of tile t+1 (issued iter t-1,
// ~5 phases of slack). Tail: stage indices clamped (junk into dead buffer),
// final vmcnt(0) after loop.
// ---------------------------------------------------------------------------
__global__ __launch_bounds__(512)
void gemm256_kernel(const ushort_t* __restrict__ A,
                    const ushort_t* __restrict__ B,
                    const float* __restrict__ bias,
                    float* __restrict__ C)
{
    constexpr int LDA = 3072;   // = K = ldb = ldc
    constexpr int NT  = 48;     // K / 64
    constexpr int NBX = 12;     // N / 256

    __shared__ ushort_t smem_u[65536];          // 128 KiB
    char* const smem = (char*)smem_u;

    const int t    = threadIdx.x;
    const int lane = t & 63;
    const int wave = t >> 6;
    const int wr   = wave >> 2;        // 0..1 : M half (128 rows)
    const int wc   = wave & 3;         // 0..3 : N quarter (64 cols)
    const int quad = lane >> 4;
    const int l16  = lane & 15;

    // T1: bijective XCD swizzle (768 blocks, 768 % 8 == 0)
    const int bid = blockIdx.x;
    const int sw  = (bid & 7) * 96 + (bid >> 3);
    const int bx  = sw % NBX;
    const int by  = sw / NBX;
    const int mBase = by * 256;
    const int nBase = bx * 256;

    // ---- staging addresses (pre-swizzled global source, linear LDS dst) ----
    const int prow = t >> 3;                   // 0..63
    const int cg   = (t & 7) ^ (prow & 7);     // swizzled global chunk index
    const ushort_t* const aSrc = A + (size_t)(mBase + prow) * LDA + cg * 8;
    const ushort_t* const bSrc = B + (size_t)(nBase + prow) * LDA + cg * 8;
    char* const aDst = smem + t * 16;          // + c*65536 + h*16384 (+8192)
    char* const bDst = smem + 32768 + t * 16;

#define STAGE_A(c, h, kt) do {                                              \
        const ushort_t* _s = aSrc + (size_t)(h) * 128 * LDA + (kt) * 64;    \
        char* _d = aDst + (c) * 65536 + (h) * 16384;                        \
        async_load16(_s, _d);                                               \
        async_load16(_s + 64 * LDA, _d + 8192);                             \
    } while (0)
#define STAGE_B(c, h, kt) do {                                              \
        const ushort_t* _s = bSrc + (size_t)(h) * 128 * LDA + (kt) * 64;    \
        char* _d = bDst + (c) * 65536 + (h) * 16384;                        \
        async_load16(_s, _d);                                               \
        async_load16(_s + 64 * LDA, _d + 8192);                             \
    } while (0)

    // ---- LDS read bases (bytes). chunk = (ks*4+quad) ^ (row&7); row&7==l16&7
    const int s0  = ((0 + quad) ^ (l16 & 7)) << 4;      // ks=0
    const int s1  = ((4 + quad) ^ (l16 & 7)) << 4;      // ks=1
    const int aRd = wr * 16384 + l16 * 128;
    const int bRd = 32768 + (wc >> 1) * 16384 + ((wc & 1) * 64 + l16) * 128;

    floatx4 acc[8][4] = {};
    bf16x8 af[8][2];
    bf16x8 bfr[2][2];

    // ---- prologue: tiles 0 and 1 fully issued (16 loads); land tile 0 ----
    STAGE_A(0, 0, 0); STAGE_A(0, 1, 0);
    STAGE_B(0, 0, 0); STAGE_B(0, 1, 0);
    STAGE_A(1, 0, 1); STAGE_A(1, 1, 1);
    STAGE_B(1, 0, 1); STAGE_B(1, 1, 1);
    asm volatile("s_waitcnt vmcnt(8)" ::: "memory");
    __builtin_amdgcn_s_barrier();
    __builtin_amdgcn_sched_barrier(0);

    int cur = 0;
    for (int kt = 0; kt < NT; ++kt) {
        const int cb  = cur << 16;
        const int ktA = (kt + 2 < NT) ? kt + 2 : NT - 1;   // clamp tail

        // ---------------- P1: af[0..3], bf[0..1] (no stage) -----------------
#pragma unroll
        for (int mi = 0; mi < 4; ++mi) {
            af[mi][0] = *(const bf16x8*)(smem + cb + aRd + mi * 2048 + s0);
            af[mi][1] = *(const bf16x8*)(smem + cb + aRd + mi * 2048 + s1);
        }
#pragma unroll
        for (int nj = 0; nj < 2; ++nj) {
            bfr[nj][0] = *(const bf16x8*)(smem + cb + bRd + nj * 2048 + s0);
            bfr[nj][1] = *(const bf16x8*)(smem + cb + bRd + nj * 2048 + s1);
        }
        __builtin_amdgcn_s_barrier();
        asm volatile("s_waitcnt lgkmcnt(0)" ::: "memory");
        __builtin_amdgcn_sched_barrier(0);
        __builtin_amdgcn_s_setprio(1);
#pragma unroll
        for (int ks = 0; ks < 2; ++ks)
#pragma unroll
            for (int mi = 0; mi < 4; ++mi)
#pragma unroll
                for (int nj = 0; nj < 2; ++nj)
                    acc[mi][nj] = MFMA16(af[mi][ks], bfr[nj][ks], acc[mi][nj]);
        __builtin_amdgcn_s_setprio(0);
        __builtin_amdgcn_s_barrier();

        // ---------------- P2: af[4..7] (no stage); A(cur) released after ----
#pragma unroll
        for (int mi = 4; mi < 8; ++mi) {
            af[mi][0] = *(const bf16x8*)(smem + cb + aRd + mi * 2048 + s0);
            af[mi][1] = *(const bf16x8*)(smem + cb + aRd + mi * 2048 + s1);
        }
        __builtin_amdgcn_s_barrier();
        asm volatile("s_waitcnt lgkmcnt(0)" ::: "memory");
        __builtin_amdgcn_sched_barrier(0);
        __builtin_amdgcn_s_setprio(1);
#pragma unroll
        for (int ks = 0; ks < 2; ++ks)
#pragma unroll
            for (int mi = 4; mi < 8; ++mi)
#pragma unroll
                for (int nj = 0; nj < 2; ++nj)
                    acc[mi][nj] = MFMA16(af[mi][ks], bfr[nj][ks], acc[mi][nj]);
        __builtin_amdgcn_s_setprio(0);
        __builtin_amdgcn_s_barrier();

        // ---------------- P3: bf[2..3]; stage A(t+2) -> cur -----------------
#pragma unroll
        for (int nj = 0; nj < 2; ++nj) {
            bfr[nj][0] = *(const bf16x8*)(smem + cb + bRd + (2 + nj) * 2048 + s0);
            bfr[nj][1] = *(const bf16x8*)(smem + cb + bRd + (2 + nj) * 2048 + s1);
        }
        STAGE_A(cur, 0, ktA);
        STAGE_A(cur, 1, ktA);
        __builtin_amdgcn_s_barrier();
        asm volatile("s_waitcnt lgkmcnt(0)" ::: "memory");
        __builtin_amdgcn_sched_barrier(0);
        __builtin_amdgcn_s_setprio(1);
#pragma unroll
        for (int ks = 0; ks < 2; ++ks)
#pragma unroll
            for (int mi = 0; mi < 4; ++mi)
#pragma unroll
                for (int nj = 0; nj < 2; ++nj)
                    acc[mi][2 + nj] = MFMA16(af[mi][ks], bfr[nj][ks], acc[mi][2 + nj]);
        __builtin_amdgcn_s_setprio(0);
        __builtin_amdgcn_s_barrier();

        // ---------------- P4: stage B(t+2) -> cur; MFMA from regs; vmcnt ----
        STAGE_B(cur, 0, ktA);
        STAGE_B(cur, 1, ktA);
        __builtin_amdgcn_s_barrier();
        __builtin_amdgcn_sched_barrier(0);
        __builtin_amdgcn_s_setprio(1);
#pragma unroll
        for (int ks = 0; ks < 2; ++ks)
#pragma unroll
            for (int mi = 4; mi < 8; ++mi)
#pragma unroll
                for (int nj = 0; nj < 2; ++nj)
                    acc[mi][2 + nj] = MFMA16(af[mi][ks], bfr[nj][ks], acc[mi][2 + nj]);
        __builtin_amdgcn_s_setprio(0);
        __builtin_amdgcn_sched_barrier(0);
        asm volatile("s_waitcnt vmcnt(8)" ::: "memory");   // tile t+1 resident
        __builtin_amdgcn_s_barrier();

        cur ^= 1;
    }

    // Drain tail junk DMAs before LDS is released to the next workgroup.
    asm volatile("s_waitcnt vmcnt(0)" ::: "memory");

    // Epilogue. C/D layout: col = lane&15, row = quad*4 + reg.
#pragma unroll
    for (int ni = 0; ni < 4; ++ni) {
        const int col = nBase + wc * 64 + ni * 16 + l16;
        const float bv = bias[col];
#pragma unroll
        for (int mi = 0; mi < 8; ++mi) {
            const int row0 = mBase + wr * 128 + mi * 16 + quad * 4;
            float* cp = C + (size_t)row0 * LDA + col;
#pragma unroll
            for (int r = 0; r < 4; ++r)
                cp[(size_t)r * LDA] = acc[mi][ni][r] + bv;
        }
    }
#undef STAGE_A
#undef STAGE_B
}

extern "C" void kernel_launch(void* const* d_in, const int* in_sizes, int n_in,
                              void* d_out, int out_size, void* d_ws, size_t ws_size,
                              hipStream_t stream) {
    // Inputs (fp32): x[4,4096,3072], W[3072,3072], b[3072],
    //                lora_A[4,32,3072], lora_B[4,3072,32]
    const float* x  = (const float*)d_in[0];
    const float* W  = (const float*)d_in[1];
    const float* b  = (const float*)d_in[2];
    const float* lA = (const float*)d_in[3];
    const float* lB = (const float*)d_in[4];
    float* out = (float*)d_out;

    constexpr int M = 4 * 4096;        // 16384
    constexpr int N = 3072;
    constexpr int K = 3072;
    constexpr size_t nX  = (size_t)M * K;     // 50331648
    constexpr size_t nW  = (size_t)N * K;     //  9437184
    constexpr size_t nT  = (size_t)128 * K;   //   393216

    // Workspace (bf16 elems): xb | Weffb | Bp | At
    ushort_t* xb    = (ushort_t*)d_ws;
    ushort_t* Weffb = xb + nX;
    ushort_t* Bp    = Weffb + nW;
    ushort_t* At    = Bp + nT;

    // 1) x -> bf16 (8 elem/thread)
    cvt_kernel<<<nX / 8 / 256, 256, 0, stream>>>(x, xb, (int)(nX / 8));

    // 2) fused LoRA factor transposes (bf16 [3072,128], inner dim contiguous)
    transpose_lora_kernel<<<2 * (nT / 256), 256, 0, stream>>>(lB, lA, Bp, At);

    // 3) Weff[n,kk] = sum_j B'[n,j]*A^T[kk,j] + W[n,kk], bf16 out. K=128 -> KT=4.
    gemm_bt_kernel<4, false, true><<<dim3(N / 128, N / 128), 256, 0, stream>>>(
        Bp, 128, At, 128, W, nullptr, Weffb, N);

    // 4) out = xb @ Weff^T + b, fp32 out. 256^2 deep-pipelined, 768 blocks.
    gemm256_kernel<<<(M / 256) * (N / 256), 512, 0, stream>>>(xb, Weffb, b, out);
}

// Round 3
// 633.365 us; speedup vs baseline: 1.0591x; 1.0591x over previous
//
#include <hip/hip_runtime.h>
#include <hip/hip_bf16.h>

// StackedLoRALinear on MI355X (gfx950). fp32 in/out, bf16 MFMA inside.
//
// Algebraic fold: out = x @ Weff^T + b, where
//   Weff = W + B' @ A_all,  B'[n,j=d*32+r] = lora_B[d,n,r],  A_all = lora_A flat [128,3072]
// Pipeline:
//   1. cvt x -> bf16 (8 elem/thread)
//   2. fused transpose-convert lora_B -> B' and lora_A -> A^T (bf16 [3072,128])
//   3. Weff = B' @ (A^T)^T + W  via 128^2 MFMA GEMM (KT=4, ADD_MAT, bf16 out)
//   4. out = xb @ Weff^T + b    via 256^2 MFMA GEMM, A-dbuf + B-TRIPLE buffer
//
// Step 4 schedule (v3 = v1 spread-stages + deeper B prefetch):
//   A double-buffered (2 x 32 KiB), B triple-buffered (3 x 32 KiB) = 160 KiB.
//   iter t: P1 read af[0..3]+bf[0..1], stage B(t+2)h0   (B region (t+2)%3 free
//           P2 read af[4..7],          stage B(t+2)h1    since iter t-1 P3)
//           P3 read bf[2..3],          stage A(t+2)h0   (A region freed at P2)
//           P4 stage A(t+2)h1; vmcnt(8); MFMA from regs
//   One half-tile staged per phase (m196: clustering regresses). vmcnt(8)
//   drains tile t+1, whose loads were ALL issued a full iteration (>=4 phases)
//   earlier. Never vmcnt(0) in the main loop.

typedef unsigned short ushort_t;
typedef short bf16x8 __attribute__((ext_vector_type(8)));   // 8 bf16 = 4 VGPRs
typedef float floatx4 __attribute__((ext_vector_type(4)));
typedef unsigned short ushortx4 __attribute__((ext_vector_type(4)));
typedef unsigned short ushortx8 __attribute__((ext_vector_type(8)));

__device__ __forceinline__ ushort_t f2bf(float f) {
    __hip_bfloat16 h = __float2bfloat16(f);
    return *(ushort_t*)&h;
}

__device__ __forceinline__ void async_load16(const void* g, void* l) {
    __builtin_amdgcn_global_load_lds(
        (const __attribute__((address_space(1))) void*)g,
        (__attribute__((address_space(3))) void*)l,
        16, 0, 0);
}

#define MFMA16(a, b, c) __builtin_amdgcn_mfma_f32_16x16x32_bf16(a, b, c, 0, 0, 0)

// fp32 -> bf16, 8 elements/thread. n8 = n/8.
__global__ __launch_bounds__(256)
void cvt_kernel(const float* __restrict__ in, ushort_t* __restrict__ out, int n8) {
    int i = blockIdx.x * 256 + threadIdx.x;
    if (i < n8) {
        const float4 v0 = ((const float4*)in)[2 * i];
        const float4 v1 = ((const float4*)in)[2 * i + 1];
        ushortx8 o = { f2bf(v0.x), f2bf(v0.y), f2bf(v0.z), f2bf(v0.w),
                       f2bf(v1.x), f2bf(v1.y), f2bf(v1.z), f2bf(v1.w) };
        ((ushortx8*)out)[i] = o;
    }
}

// Fused LoRA factor transposes. Blocks [0,1536): B', blocks [1536,3072): A^T.
// B'[n*128 + d*32 + r] = bf16(lora_B[d*N*32 + n*32 + r]);  N=3072
// A^T[kk*128 + j]      = bf16(lora_A[j*3072 + kk]);  (lora_A flat = [128,3072])
__global__ __launch_bounds__(256)
void transpose_lora_kernel(const float* __restrict__ lb,
                           const float* __restrict__ la,
                           ushort_t* __restrict__ outB,
                           ushort_t* __restrict__ outA) {
    int bid = blockIdx.x;
    if (bid < 1536) {
        int idx = bid * 256 + threadIdx.x;      // 0 .. 393215
        int n = idx >> 7;
        int j = idx & 127;
        int d = j >> 5, r = j & 31;
        outB[idx] = f2bf(lb[(size_t)d * (3072 * 32) + (size_t)n * 32 + r]);
    } else {
        int idx = (bid - 1536) * 256 + threadIdx.x;
        int kk = idx >> 7;
        int j  = idx & 127;
        outA[idx] = f2bf(la[(size_t)j * 3072 + kk]);
    }
}

// ---------------------------------------------------------------------------
// 128^2 "B-transposed" GEMM (kept for the tiny Weff build, KT=4).
// ---------------------------------------------------------------------------
template <int KT, bool OUT_F32, bool ADD_MAT>
__global__ __launch_bounds__(256)
void gemm_bt_kernel(const ushort_t* __restrict__ A, int lda,
                    const ushort_t* __restrict__ B, int ldb,
                    const float* __restrict__ Cadd,   // [M,ldc] fp32 if ADD_MAT
                    const float* __restrict__ bias,   // [N] fp32 or null
                    void* __restrict__ Cv, int ldc)
{
    __shared__ ushort_t As[128 * 32];   // 8 KB
    __shared__ ushort_t Bs[128 * 32];   // 8 KB

    const int t    = threadIdx.x;
    const int lane = t & 63;
    const int wave = t >> 6;
    const int wr   = wave >> 1, wc = wave & 1;
    const int quad = lane >> 4, l16 = lane & 15;

    const int mBase = blockIdx.y * 128;
    const int nBase = blockIdx.x * 128;

    floatx4 acc[4][4] = {};

    const int p0 = t,       r0 = p0 >> 2, g0 = ((p0 & 3) ^ ((r0 >> 1) & 3)) << 3;
    const int p1 = t + 256, r1 = p1 >> 2, g1 = ((p1 & 3) ^ ((r1 >> 1) & 3)) << 3;
    const int qs = (quad ^ ((l16 >> 1) & 3)) << 3;

    for (int kt = 0; kt < KT; ++kt) {
        const int ko = kt * 32;

        async_load16(A + (size_t)(mBase + r0) * lda + ko + g0, &As[p0 * 8]);
        async_load16(A + (size_t)(mBase + r1) * lda + ko + g1, &As[p1 * 8]);
        async_load16(B + (size_t)(nBase + r0) * ldb + ko + g0, &Bs[p0 * 8]);
        async_load16(B + (size_t)(nBase + r1) * ldb + ko + g1, &Bs[p1 * 8]);

        __syncthreads();

        bf16x8 af[4], bf[4];
#pragma unroll
        for (int mi = 0; mi < 4; ++mi)
            af[mi] = *(const bf16x8*)&As[(wr * 64 + mi * 16 + l16) * 32 + qs];
#pragma unroll
        for (int ni = 0; ni < 4; ++ni)
            bf[ni] = *(const bf16x8*)&Bs[(wc * 64 + ni * 16 + l16) * 32 + qs];

#pragma unroll
        for (int mi = 0; mi < 4; ++mi)
#pragma unroll
            for (int ni = 0; ni < 4; ++ni)
                acc[mi][ni] = MFMA16(af[mi], bf[ni], acc[mi][ni]);

        __syncthreads();
    }

#pragma unroll
    for (int ni = 0; ni < 4; ++ni) {
        const int col = nBase + wc * 64 + ni * 16 + l16;
        const float bv = bias ? bias[col] : 0.0f;
#pragma unroll
        for (int mi = 0; mi < 4; ++mi) {
            const int row = mBase + wr * 64 + mi * 16 + quad * 4;
#pragma unroll
            for (int r = 0; r < 4; ++r) {
                float v = acc[mi][ni][r] + bv;
                if (ADD_MAT) v += Cadd[(size_t)(row + r) * ldc + col];
                if (OUT_F32) {
                    ((float*)Cv)[(size_t)(row + r) * ldc + col] = v;
                } else {
                    ((ushort_t*)Cv)[(size_t)(row + r) * ldc + col] = f2bf(v);
                }
            }
        }
    }
}

// ---------------------------------------------------------------------------
// Main GEMM: 256x256 tile, BK=64, 8 waves (2M x 4N), 4 phases/K-tile.
// C[m,n] = sum_k A[m,k]*B[n,k] + bias[n]; A=[16384,3072], B=[3072,3072] bf16.
//
// LDS (160 KiB): A regions {0, 32768} (parity t&1), B regions
// {65536, 98304, 131072} (t%3). Each region = 2 halves x 16 KiB (128 rows x
// 64 cols). Slot p (16 B) at row=p>>3, chunk s=p&7 holds global chunk
// s ^ (row&7) (XOR swizzle -> conflict-free ds_read_b128; write side linear
// for global_load_lds, source address pre-swizzled).
// ---------------------------------------------------------------------------
__global__ __launch_bounds__(512)
void gemm256_kernel(const ushort_t* __restrict__ A,
                    const ushort_t* __restrict__ B,
                    const float* __restrict__ bias,
                    float* __restrict__ C)
{
    constexpr int LDA = 3072;   // = K = ldb = ldc
    constexpr int NT  = 48;     // K / 64
    constexpr int NBX = 12;     // N / 256

    __shared__ ushort_t smem_u[81920];          // 160 KiB
    char* const smem = (char*)smem_u;

    const int t    = threadIdx.x;
    const int lane = t & 63;
    const int wave = t >> 6;
    const int wr   = wave >> 2;        // 0..1 : M half (128 rows)
    const int wc   = wave & 3;         // 0..3 : N quarter (64 cols)
    const int quad = lane >> 4;
    const int l16  = lane & 15;

    // T1: bijective XCD swizzle (768 blocks, 768 % 8 == 0)
    const int bid = blockIdx.x;
    const int sw  = (bid & 7) * 96 + (bid >> 3);
    const int bx  = sw % NBX;
    const int by  = sw / NBX;
    const int mBase = by * 256;
    const int nBase = bx * 256;

    // ---- staging addresses (pre-swizzled global source, linear LDS dst) ----
    const int prow = t >> 3;                   // 0..63
    const int cg   = (t & 7) ^ (prow & 7);     // swizzled global chunk index
    const ushort_t* const aSrc = A + (size_t)(mBase + prow) * LDA + cg * 8;
    const ushort_t* const bSrc = B + (size_t)(nBase + prow) * LDA + cg * 8;

#define STAGE_A(off, h, ktv) do {                                           \
        const ushort_t* _s = aSrc + (size_t)(h) * 128 * LDA + (ktv) * 64;   \
        char* _d = smem + (off) + (h) * 16384 + t * 16;                     \
        async_load16(_s, _d);                                               \
        async_load16(_s + 64 * LDA, _d + 8192);                             \
    } while (0)
#define STAGE_B(off, h, ktv) do {                                           \
        const ushort_t* _s = bSrc + (size_t)(h) * 128 * LDA + (ktv) * 64;   \
        char* _d = smem + (off) + (h) * 16384 + t * 16;                     \
        async_load16(_s, _d);                                               \
        async_load16(_s + 64 * LDA, _d + 8192);                             \
    } while (0)

    // ---- LDS read bases (bytes). chunk = (ks*4+quad) ^ (row&7); row&7==l16&7
    const int s0  = ((0 + quad) ^ (l16 & 7)) << 4;      // ks=0
    const int s1  = ((4 + quad) ^ (l16 & 7)) << 4;      // ks=1
    const int aRdB = wr * 16384 + l16 * 128;
    const int bRdB = (wc >> 1) * 16384 + ((wc & 1) * 64 + l16) * 128;

    floatx4 acc[8][4] = {};
    bf16x8 af[8][2];
    bf16x8 bfr[2][2];

    // ---- prologue: tile0 (A@0, B@65536) + tile1 (A@32768, B@98304) ----
    STAGE_A(0,      0, 0); STAGE_A(0,      1, 0);
    STAGE_B(65536,  0, 0); STAGE_B(65536,  1, 0);
    STAGE_A(32768,  0, 1); STAGE_A(32768,  1, 1);
    STAGE_B(98304,  0, 1); STAGE_B(98304,  1, 1);
    asm volatile("s_waitcnt vmcnt(8)" ::: "memory");   // tile0 resident
    __builtin_amdgcn_s_barrier();
    __builtin_amdgcn_sched_barrier(0);

    int aOff = 0;          // A region read this iter == A(t+2) stage target
    int bRdO = 65536;      // B region read this iter  (t%3)
    int bStO = 131072;     // B(t+2) stage target      ((t+2)%3)

    for (int kt = 0; kt < NT; ++kt) {
        const int ktN = (kt + 2 < NT) ? kt + 2 : NT - 1;   // clamp tail

        // ---------------- P1: af[0..3], bf[0..1]; stage B(t+2)h0 ------------
#pragma unroll
        for (int mi = 0; mi < 4; ++mi) {
            af[mi][0] = *(const bf16x8*)(smem + aOff + aRdB + mi * 2048 + s0);
            af[mi][1] = *(const bf16x8*)(smem + aOff + aRdB + mi * 2048 + s1);
        }
#pragma unroll
        for (int nj = 0; nj < 2; ++nj) {
            bfr[nj][0] = *(const bf16x8*)(smem + bRdO + bRdB + nj * 2048 + s0);
            bfr[nj][1] = *(const bf16x8*)(smem + bRdO + bRdB + nj * 2048 + s1);
        }
        STAGE_B(bStO, 0, ktN);
        __builtin_amdgcn_s_barrier();
        asm volatile("s_waitcnt lgkmcnt(0)" ::: "memory");
        __builtin_amdgcn_sched_barrier(0);
        __builtin_amdgcn_s_setprio(1);
#pragma unroll
        for (int ks = 0; ks < 2; ++ks)
#pragma unroll
            for (int mi = 0; mi < 4; ++mi)
#pragma unroll
                for (int nj = 0; nj < 2; ++nj)
                    acc[mi][nj] = MFMA16(af[mi][ks], bfr[nj][ks], acc[mi][nj]);
        __builtin_amdgcn_s_setprio(0);
        __builtin_amdgcn_s_barrier();

        // ---------------- P2: af[4..7]; stage B(t+2)h1 ----------------------
#pragma unroll
        for (int mi = 4; mi < 8; ++mi) {
            af[mi][0] = *(const bf16x8*)(smem + aOff + aRdB + mi * 2048 + s0);
            af[mi][1] = *(const bf16x8*)(smem + aOff + aRdB + mi * 2048 + s1);
        }
        STAGE_B(bStO, 1, ktN);
        __builtin_amdgcn_s_barrier();
        asm volatile("s_waitcnt lgkmcnt(0)" ::: "memory");
        __builtin_amdgcn_sched_barrier(0);
        __builtin_amdgcn_s_setprio(1);
#pragma unroll
        for (int ks = 0; ks < 2; ++ks)
#pragma unroll
            for (int mi = 4; mi < 8; ++mi)
#pragma unroll
                for (int nj = 0; nj < 2; ++nj)
                    acc[mi][nj] = MFMA16(af[mi][ks], bfr[nj][ks], acc[mi][nj]);
        __builtin_amdgcn_s_setprio(0);
        __builtin_amdgcn_s_barrier();

        // ---------------- P3: bf[2..3]; stage A(t+2)h0 (A released @P2) -----
#pragma unroll
        for (int nj = 0; nj < 2; ++nj) {
            bfr[nj][0] = *(const bf16x8*)(smem + bRdO + bRdB + (2 + nj) * 2048 + s0);
            bfr[nj][1] = *(const bf16x8*)(smem + bRdO + bRdB + (2 + nj) * 2048 + s1);
        }
        STAGE_A(aOff, 0, ktN);
        __builtin_amdgcn_s_barrier();
        asm volatile("s_waitcnt lgkmcnt(0)" ::: "memory");
        __builtin_amdgcn_sched_barrier(0);
        __builtin_amdgcn_s_setprio(1);
#pragma unroll
        for (int ks = 0; ks < 2; ++ks)
#pragma unroll
            for (int mi = 0; mi < 4; ++mi)
#pragma unroll
                for (int nj = 0; nj < 2; ++nj)
                    acc[mi][2 + nj] = MFMA16(af[mi][ks], bfr[nj][ks], acc[mi][2 + nj]);
        __builtin_amdgcn_s_setprio(0);
        __builtin_amdgcn_s_barrier();

        // ---------------- P4: stage A(t+2)h1; vmcnt(8); MFMA from regs ------
        STAGE_A(aOff, 1, ktN);
        asm volatile("s_waitcnt vmcnt(8)" ::: "memory");   // tile t+1 resident
        __builtin_amdgcn_s_barrier();
        __builtin_amdgcn_sched_barrier(0);
        __builtin_amdgcn_s_setprio(1);
#pragma unroll
        for (int ks = 0; ks < 2; ++ks)
#pragma unroll
            for (int mi = 4; mi < 8; ++mi)
#pragma unroll
                for (int nj = 0; nj < 2; ++nj)
                    acc[mi][2 + nj] = MFMA16(af[mi][ks], bfr[nj][ks], acc[mi][2 + nj]);
        __builtin_amdgcn_s_setprio(0);
        __builtin_amdgcn_s_barrier();

        // rotate buffers
        aOff ^= 32768;
        bRdO = (bRdO == 131072) ? 65536 : bRdO + 32768;
        bStO = (bStO == 131072) ? 65536 : bStO + 32768;
    }

    // Drain tail junk DMAs before LDS is released to the next workgroup.
    asm volatile("s_waitcnt vmcnt(0)" ::: "memory");

    // Epilogue. C/D layout: col = lane&15, row = quad*4 + reg.
#pragma unroll
    for (int ni = 0; ni < 4; ++ni) {
        const int col = nBase + wc * 64 + ni * 16 + l16;
        const float bv = bias[col];
#pragma unroll
        for (int mi = 0; mi < 8; ++mi) {
            const int row0 = mBase + wr * 128 + mi * 16 + quad * 4;
            float* cp = C + (size_t)row0 * LDA + col;
#pragma unroll
            for (int r = 0; r < 4; ++r)
                cp[(size_t)r * LDA] = acc[mi][ni][r] + bv;
        }
    }
#undef STAGE_A
#undef STAGE_B
}

extern "C" void kernel_launch(void* const* d_in, const int* in_sizes, int n_in,
                              void* d_out, int out_size, void* d_ws, size_t ws_size,
                              hipStream_t stream) {
    // Inputs (fp32): x[4,4096,3072], W[3072,3072], b[3072],
    //                lora_A[4,32,3072], lora_B[4,3072,32]
    const float* x  = (const float*)d_in[0];
    const float* W  = (const float*)d_in[1];
    const float* b  = (const float*)d_in[2];
    const float* lA = (const float*)d_in[3];
    const float* lB = (const float*)d_in[4];
    float* out = (float*)d_out;

    constexpr int M = 4 * 4096;        // 16384
    constexpr int N = 3072;
    constexpr int K = 3072;
    constexpr size_t nX  = (size_t)M * K;     // 50331648
    constexpr size_t nW  = (size_t)N * K;     //  9437184
    constexpr size_t nT  = (size_t)128 * K;   //   393216

    // Workspace (bf16 elems): xb | Weffb | Bp | At
    ushort_t* xb    = (ushort_t*)d_ws;
    ushort_t* Weffb = xb + nX;
    ushort_t* Bp    = Weffb + nW;
    ushort_t* At    = Bp + nT;

    // 1) x -> bf16 (8 elem/thread)
    cvt_kernel<<<nX / 8 / 256, 256, 0, stream>>>(x, xb, (int)(nX / 8));

    // 2) fused LoRA factor transposes (bf16 [3072,128], inner dim contiguous)
    transpose_lora_kernel<<<2 * (nT / 256), 256, 0, stream>>>(lB, lA, Bp, At);

    // 3) Weff[n,kk] = sum_j B'[n,j]*A^T[kk,j] + W[n,kk], bf16 out. K=128 -> KT=4.
    gemm_bt_kernel<4, false, true><<<dim3(N / 128, N / 128), 256, 0, stream>>>(
        Bp, 128, At, 128, W, nullptr, Weffb, N);

    // 4) out = xb @ Weff^T + b, fp32 out. 256^2 B-triple-buffered, 768 blocks.
    gemm256_kernel<<<(M / 256) * (N / 256), 512, 0, stream>>>(xb, Weffb, b, out);
}

// Round 4
// 630.677 us; speedup vs baseline: 1.0636x; 1.0043x over previous
//
#include <hip/hip_runtime.h>
#include <hip/hip_bf16.h>

// StackedLoRALinear on MI355X (gfx950). fp32 in/out, bf16 MFMA inside.
//
// Algebraic fold: out = x @ Weff^T + b, where
//   Weff = W + B' @ A_all,  B'[n,j=d*32+r] = lora_B[d,n,r],  A_all = lora_A flat [128,3072]
// Pipeline:
//   1. cvt x -> bf16 (8 elem/thread)
//   2. fused transpose-convert lora_B -> B' and lora_A -> A^T (bf16 [3072,128])
//   3. Weff = B' @ (A^T)^T + W  via 128^2 MFMA GEMM (KT=4, ADD_MAT, bf16 out)
//   4. out = xb @ Weff^T + b    via 256^2 MFMA GEMM, 2-barrier K-tile (v4)
//
// v4 schedule rationale: v1/v3's 8-barrier-per-K-tile lockstep serialized the
// DS pipe against the matrix pipe (reads ~2300cy + MFMA ~2480cy added, not
// overlapped -> 5080cy/K-tile, MfmaUtil 45%). v4 uses 2 barriers/K-tile and
// lets the compiler's counted-lgkmcnt scheduling overlap fragment reads with
// MFMA within each wave:
//   [stage B(t+2) early]  half1: 24 ds_read + 32 MFMA (bf[0..1]) interleaved
//   lgkmcnt(0); barrier#1              (all waves' reads executed)
//   [stage A(t+2) -> parity region just released]
//   half2: 32 MFMA pure-register (bf[2..3]) hides DMA issue
//   vmcnt(8); barrier#2                (tile t+1 resident, cross-wave)
// A double-buffered (2x32 KiB), B triple-buffered (3x32 KiB) = 160 KiB LDS.

typedef unsigned short ushort_t;
typedef short bf16x8 __attribute__((ext_vector_type(8)));   // 8 bf16 = 4 VGPRs
typedef float floatx4 __attribute__((ext_vector_type(4)));
typedef unsigned short ushortx4 __attribute__((ext_vector_type(4)));
typedef unsigned short ushortx8 __attribute__((ext_vector_type(8)));

__device__ __forceinline__ ushort_t f2bf(float f) {
    __hip_bfloat16 h = __float2bfloat16(f);
    return *(ushort_t*)&h;
}

__device__ __forceinline__ void async_load16(const void* g, void* l) {
    __builtin_amdgcn_global_load_lds(
        (const __attribute__((address_space(1))) void*)g,
        (__attribute__((address_space(3))) void*)l,
        16, 0, 0);
}

#define MFMA16(a, b, c) __builtin_amdgcn_mfma_f32_16x16x32_bf16(a, b, c, 0, 0, 0)

// fp32 -> bf16, 8 elements/thread. n8 = n/8.
__global__ __launch_bounds__(256)
void cvt_kernel(const float* __restrict__ in, ushort_t* __restrict__ out, int n8) {
    int i = blockIdx.x * 256 + threadIdx.x;
    if (i < n8) {
        const float4 v0 = ((const float4*)in)[2 * i];
        const float4 v1 = ((const float4*)in)[2 * i + 1];
        ushortx8 o = { f2bf(v0.x), f2bf(v0.y), f2bf(v0.z), f2bf(v0.w),
                       f2bf(v1.x), f2bf(v1.y), f2bf(v1.z), f2bf(v1.w) };
        ((ushortx8*)out)[i] = o;
    }
}

// Fused LoRA factor transposes. Blocks [0,1536): B', blocks [1536,3072): A^T.
// B'[n*128 + d*32 + r] = bf16(lora_B[d*N*32 + n*32 + r]);  N=3072
// A^T[kk*128 + j]      = bf16(lora_A[j*3072 + kk]);  (lora_A flat = [128,3072])
__global__ __launch_bounds__(256)
void transpose_lora_kernel(const float* __restrict__ lb,
                           const float* __restrict__ la,
                           ushort_t* __restrict__ outB,
                           ushort_t* __restrict__ outA) {
    int bid = blockIdx.x;
    if (bid < 1536) {
        int idx = bid * 256 + threadIdx.x;      // 0 .. 393215
        int n = idx >> 7;
        int j = idx & 127;
        int d = j >> 5, r = j & 31;
        outB[idx] = f2bf(lb[(size_t)d * (3072 * 32) + (size_t)n * 32 + r]);
    } else {
        int idx = (bid - 1536) * 256 + threadIdx.x;
        int kk = idx >> 7;
        int j  = idx & 127;
        outA[idx] = f2bf(la[(size_t)j * 3072 + kk]);
    }
}

// ---------------------------------------------------------------------------
// 128^2 "B-transposed" GEMM (kept for the tiny Weff build, KT=4).
// ---------------------------------------------------------------------------
template <int KT, bool OUT_F32, bool ADD_MAT>
__global__ __launch_bounds__(256)
void gemm_bt_kernel(const ushort_t* __restrict__ A, int lda,
                    const ushort_t* __restrict__ B, int ldb,
                    const float* __restrict__ Cadd,   // [M,ldc] fp32 if ADD_MAT
                    const float* __restrict__ bias,   // [N] fp32 or null
                    void* __restrict__ Cv, int ldc)
{
    __shared__ ushort_t As[128 * 32];   // 8 KB
    __shared__ ushort_t Bs[128 * 32];   // 8 KB

    const int t    = threadIdx.x;
    const int lane = t & 63;
    const int wave = t >> 6;
    const int wr   = wave >> 1, wc = wave & 1;
    const int quad = lane >> 4, l16 = lane & 15;

    const int mBase = blockIdx.y * 128;
    const int nBase = blockIdx.x * 128;

    floatx4 acc[4][4] = {};

    const int p0 = t,       r0 = p0 >> 2, g0 = ((p0 & 3) ^ ((r0 >> 1) & 3)) << 3;
    const int p1 = t + 256, r1 = p1 >> 2, g1 = ((p1 & 3) ^ ((r1 >> 1) & 3)) << 3;
    const int qs = (quad ^ ((l16 >> 1) & 3)) << 3;

    for (int kt = 0; kt < KT; ++kt) {
        const int ko = kt * 32;

        async_load16(A + (size_t)(mBase + r0) * lda + ko + g0, &As[p0 * 8]);
        async_load16(A + (size_t)(mBase + r1) * lda + ko + g1, &As[p1 * 8]);
        async_load16(B + (size_t)(nBase + r0) * ldb + ko + g0, &Bs[p0 * 8]);
        async_load16(B + (size_t)(nBase + r1) * ldb + ko + g1, &Bs[p1 * 8]);

        __syncthreads();

        bf16x8 af[4], bf[4];
#pragma unroll
        for (int mi = 0; mi < 4; ++mi)
            af[mi] = *(const bf16x8*)&As[(wr * 64 + mi * 16 + l16) * 32 + qs];
#pragma unroll
        for (int ni = 0; ni < 4; ++ni)
            bf[ni] = *(const bf16x8*)&Bs[(wc * 64 + ni * 16 + l16) * 32 + qs];

#pragma unroll
        for (int mi = 0; mi < 4; ++mi)
#pragma unroll
            for (int ni = 0; ni < 4; ++ni)
                acc[mi][ni] = MFMA16(af[mi], bf[ni], acc[mi][ni]);

        __syncthreads();
    }

#pragma unroll
    for (int ni = 0; ni < 4; ++ni) {
        const int col = nBase + wc * 64 + ni * 16 + l16;
        const float bv = bias ? bias[col] : 0.0f;
#pragma unroll
        for (int mi = 0; mi < 4; ++mi) {
            const int row = mBase + wr * 64 + mi * 16 + quad * 4;
#pragma unroll
            for (int r = 0; r < 4; ++r) {
                float v = acc[mi][ni][r] + bv;
                if (ADD_MAT) v += Cadd[(size_t)(row + r) * ldc + col];
                if (OUT_F32) {
                    ((float*)Cv)[(size_t)(row + r) * ldc + col] = v;
                } else {
                    ((ushort_t*)Cv)[(size_t)(row + r) * ldc + col] = f2bf(v);
                }
            }
        }
    }
}

// ---------------------------------------------------------------------------
// Main GEMM: 256x256 tile, BK=64, 8 waves (2M x 4N), 2 barriers/K-tile.
// C[m,n] = sum_k A[m,k]*B[n,k] + bias[n]; A=[16384,3072], B=[3072,3072] bf16.
//
// LDS (160 KiB): A regions {0, 32768} (parity t&1), B regions
// {65536, 98304, 131072} (t%3). Each region = 2 halves x 16 KiB (128 rows x
// 64 cols). Slot p (16 B) at row=p>>3, chunk s=p&7 holds global chunk
// s ^ (row&7) (XOR swizzle -> conflict-free ds_read_b128; write side linear
// for global_load_lds, source address pre-swizzled).
//
// Sync proof sketch (per K-tile t):
//   early STAGE_B -> region (t+2)%3: last read in tile t-1, drained before
//     its barrier#1; we are past its barrier#2. Safe.
//   STAGE_A -> parity t&1 (the region af just read): issued after barrier#1,
//     which every wave reaches only after lgkmcnt(0). Safe.
//   vmcnt(8) before barrier#2: per-wave FIFO has batch_t (8) + batch_{t-1}
//     (8); waits batch_{t-1} = tile t+1 data. barrier#2 makes it cross-wave.
//     Tile t+1 reads happen only after barrier#2. Safe.
// ---------------------------------------------------------------------------
__global__ __launch_bounds__(512)
void gemm256_kernel(const ushort_t* __restrict__ A,
                    const ushort_t* __restrict__ B,
                    const float* __restrict__ bias,
                    float* __restrict__ C)
{
    constexpr int LDA = 3072;   // = K = ldb = ldc
    constexpr int NT  = 48;     // K / 64
    constexpr int NBX = 12;     // N / 256

    __shared__ ushort_t smem_u[81920];          // 160 KiB
    char* const smem = (char*)smem_u;

    const int t    = threadIdx.x;
    const int lane = t & 63;
    const int wave = t >> 6;
    const int wr   = wave >> 2;        // 0..1 : M half (128 rows)
    const int wc   = wave & 3;         // 0..3 : N quarter (64 cols)
    const int quad = lane >> 4;
    const int l16  = lane & 15;

    // T1: bijective XCD swizzle (768 blocks, 768 % 8 == 0)
    const int bid = blockIdx.x;
    const int sw  = (bid & 7) * 96 + (bid >> 3);
    const int bx  = sw % NBX;
    const int by  = sw / NBX;
    const int mBase = by * 256;
    const int nBase = bx * 256;

    // ---- staging addresses (pre-swizzled global source, linear LDS dst) ----
    const int prow = t >> 3;                   // 0..63
    const int cg   = (t & 7) ^ (prow & 7);     // swizzled global chunk index
    const ushort_t* const aSrc = A + (size_t)(mBase + prow) * LDA + cg * 8;
    const ushort_t* const bSrc = B + (size_t)(nBase + prow) * LDA + cg * 8;

#define STAGE_A(off, h, ktv) do {                                           \
        const ushort_t* _s = aSrc + (size_t)(h) * 128 * LDA + (ktv) * 64;   \
        char* _d = smem + (off) + (h) * 16384 + t * 16;                     \
        async_load16(_s, _d);                                               \
        async_load16(_s + 64 * LDA, _d + 8192);                             \
    } while (0)
#define STAGE_B(off, h, ktv) do {                                           \
        const ushort_t* _s = bSrc + (size_t)(h) * 128 * LDA + (ktv) * 64;   \
        char* _d = smem + (off) + (h) * 16384 + t * 16;                     \
        async_load16(_s, _d);                                               \
        async_load16(_s + 64 * LDA, _d + 8192);                             \
    } while (0)

    // ---- LDS read bases (bytes). chunk = (ks*4+quad) ^ (row&7); row&7==l16&7
    const int s0  = ((0 + quad) ^ (l16 & 7)) << 4;      // ks=0
    const int s1  = ((4 + quad) ^ (l16 & 7)) << 4;      // ks=1
    const int aRdB = wr * 16384 + l16 * 128;
    const int bRdB = (wc >> 1) * 16384 + ((wc & 1) * 64 + l16) * 128;

    floatx4 acc[8][4] = {};
    bf16x8 af[8][2];
    bf16x8 bfr[4][2];

    // ---- prologue: tile0 (A@0, B@65536) + tile1 (A@32768, B@98304) ----
    STAGE_A(0,      0, 0); STAGE_A(0,      1, 0);
    STAGE_B(65536,  0, 0); STAGE_B(65536,  1, 0);
    STAGE_A(32768,  0, 1); STAGE_A(32768,  1, 1);
    STAGE_B(98304,  0, 1); STAGE_B(98304,  1, 1);
    asm volatile("s_waitcnt vmcnt(8)" ::: "memory");   // tile0 resident
    __builtin_amdgcn_s_barrier();
    __builtin_amdgcn_sched_barrier(0);

    int aOff = 0;          // A region read this iter == A(t+2) stage target
    int bRdO = 65536;      // B region read this iter  (t%3)
    int bStO = 131072;     // B(t+2) stage target      ((t+2)%3)

    for (int kt = 0; kt < NT; ++kt) {
        const int ktN = (kt + 2 < NT) ? kt + 2 : NT - 1;   // clamp tail

        // ---- early stage: B(t+2) -> region free since tile t-1 ------------
        STAGE_B(bStO, 0, ktN);
        STAGE_B(bStO, 1, ktN);
        __builtin_amdgcn_sched_barrier(0);

        // ---- half 1: all fragment reads + MFMA on bf[0..1] ----------------
        // (no barrier between reads and MFMA: compiler emits counted lgkmcnt,
        //  so MFMA overlaps the DS pipe within and across waves)
#pragma unroll
        for (int mi = 0; mi < 8; ++mi) {
            af[mi][0] = *(const bf16x8*)(smem + aOff + aRdB + mi * 2048 + s0);
            af[mi][1] = *(const bf16x8*)(smem + aOff + aRdB + mi * 2048 + s1);
        }
#pragma unroll
        for (int nj = 0; nj < 4; ++nj) {
            bfr[nj][0] = *(const bf16x8*)(smem + bRdO + bRdB + nj * 2048 + s0);
            bfr[nj][1] = *(const bf16x8*)(smem + bRdO + bRdB + nj * 2048 + s1);
        }
#pragma unroll
        for (int ks = 0; ks < 2; ++ks)
#pragma unroll
            for (int mi = 0; mi < 8; ++mi)
#pragma unroll
                for (int nj = 0; nj < 2; ++nj)
                    acc[mi][nj] = MFMA16(af[mi][ks], bfr[nj][ks], acc[mi][nj]);

        asm volatile("s_waitcnt lgkmcnt(0)" ::: "memory");
        __builtin_amdgcn_sched_barrier(0);
        __builtin_amdgcn_s_barrier();      // #1: all waves' LDS reads done

        // ---- stage A(t+2) into the parity region just released ------------
        STAGE_A(aOff, 0, ktN);
        STAGE_A(aOff, 1, ktN);
        __builtin_amdgcn_sched_barrier(0);

        // ---- half 2: MFMA on bf[2..3], pure-register (hides DMA issue) ----
        __builtin_amdgcn_s_setprio(1);
#pragma unroll
        for (int ks = 0; ks < 2; ++ks)
#pragma unroll
            for (int mi = 0; mi < 8; ++mi)
#pragma unroll
                for (int nj = 0; nj < 2; ++nj)
                    acc[mi][2 + nj] = MFMA16(af[mi][ks], bfr[2 + nj][ks],
                                             acc[mi][2 + nj]);
        __builtin_amdgcn_s_setprio(0);
        __builtin_amdgcn_sched_barrier(0);
        asm volatile("s_waitcnt vmcnt(8)" ::: "memory");   // tile t+1 resident
        __builtin_amdgcn_s_barrier();      // #2
        __builtin_amdgcn_sched_barrier(0);

        // rotate buffers
        aOff ^= 32768;
        bRdO = (bRdO == 131072) ? 65536 : bRdO + 32768;
        bStO = (bStO == 131072) ? 65536 : bStO + 32768;
    }

    // Drain tail junk DMAs before LDS is released to the next workgroup.
    asm volatile("s_waitcnt vmcnt(0)" ::: "memory");

    // Epilogue. C/D layout: col = lane&15, row = quad*4 + reg.
#pragma unroll
    for (int ni = 0; ni < 4; ++ni) {
        const int col = nBase + wc * 64 + ni * 16 + l16;
        const float bv = bias[col];
#pragma unroll
        for (int mi = 0; mi < 8; ++mi) {
            const int row0 = mBase + wr * 128 + mi * 16 + quad * 4;
            float* cp = C + (size_t)row0 * LDA + col;
#pragma unroll
            for (int r = 0; r < 4; ++r)
                cp[(size_t)r * LDA] = acc[mi][ni][r] + bv;
        }
    }
#undef STAGE_A
#undef STAGE_B
}

extern "C" void kernel_launch(void* const* d_in, const int* in_sizes, int n_in,
                              void* d_out, int out_size, void* d_ws, size_t ws_size,
                              hipStream_t stream) {
    // Inputs (fp32): x[4,4096,3072], W[3072,3072], b[3072],
    //                lora_A[4,32,3072], lora_B[4,3072,32]
    const float* x  = (const float*)d_in[0];
    const float* W  = (const float*)d_in[1];
    const float* b  = (const float*)d_in[2];
    const float* lA = (const float*)d_in[3];
    const float* lB = (const float*)d_in[4];
    float* out = (float*)d_out;

    constexpr int M = 4 * 4096;        // 16384
    constexpr int N = 3072;
    constexpr int K = 3072;
    constexpr size_t nX  = (size_t)M * K;     // 50331648
    constexpr size_t nW  = (size_t)N * K;     //  9437184
    constexpr size_t nT  = (size_t)128 * K;   //   393216

    // Workspace (bf16 elems): xb | Weffb | Bp | At
    ushort_t* xb    = (ushort_t*)d_ws;
    ushort_t* Weffb = xb + nX;
    ushort_t* Bp    = Weffb + nW;
    ushort_t* At    = Bp + nT;

    // 1) x -> bf16 (8 elem/thread)
    cvt_kernel<<<nX / 8 / 256, 256, 0, stream>>>(x, xb, (int)(nX / 8));

    // 2) fused LoRA factor transposes (bf16 [3072,128], inner dim contiguous)
    transpose_lora_kernel<<<2 * (nT / 256), 256, 0, stream>>>(lB, lA, Bp, At);

    // 3) Weff[n,kk] = sum_j B'[n,j]*A^T[kk,j] + W[n,kk], bf16 out. K=128 -> KT=4.
    gemm_bt_kernel<4, false, true><<<dim3(N / 128, N / 128), 256, 0, stream>>>(
        Bp, 128, At, 128, W, nullptr, Weffb, N);

    // 4) out = xb @ Weff^T + b, fp32 out. 256^2 2-barrier K-tile, 768 blocks.
    gemm256_kernel<<<(M / 256) * (N / 256), 512, 0, stream>>>(xb, Weffb, b, out);
}